// Round 4
// baseline (584.417 us; speedup 1.0000x reference)
//
#include <hip/hip_runtime.h>

typedef float f32x4 __attribute__((ext_vector_type(4)));
typedef __bf16 bf16x8 __attribute__((ext_vector_type(8)));
typedef unsigned short u16;

#define DIM 2048
#define SEQ 1024
#define BSZ 2
#define NH 16
#define NKV 4
#define HD 128
#define FFNDIM 5632
#define MROWS (BSZ * SEQ)  // 2048

__device__ __forceinline__ u16 f2bf(float f) {
  union { float f; unsigned u; } v; v.f = f;
  unsigned u = v.u;
  unsigned r = (u + 0x7fffu + ((u >> 16) & 1u)) >> 16;  // RNE
  return (u16)r;
}
__device__ __forceinline__ float bf2f(u16 h) {
  union { unsigned u; float f; } v; v.u = ((unsigned)h) << 16; return v.f;
}

__device__ __forceinline__ void gld16(const void* g, void* l) {
  __builtin_amdgcn_global_load_lds(
      (const __attribute__((address_space(1))) unsigned int*)g,
      (__attribute__((address_space(3))) unsigned int*)l, 16, 0, 0);
}

// ---------- transpose + fp32->bf16 convert: W [K][N] f32  ->  Wt [N][K] bf16
__global__ __launch_bounds__(256) void kxpose(const float* __restrict__ W,
                                              u16* __restrict__ Wt,
                                              int K, int N) {
  __shared__ float t[64][65];
  int kb = blockIdx.y * 64, nb = blockIdx.x * 64;
  int tid = threadIdx.x;
#pragma unroll
  for (int it = 0; it < 16; ++it) {
    int idx = it * 256 + tid;
    int r = idx >> 6, c = idx & 63;
    t[r][c] = W[(size_t)(kb + r) * N + nb + c];
  }
  __syncthreads();
#pragma unroll
  for (int it = 0; it < 16; ++it) {
    int idx = it * 256 + tid;
    int rn = idx >> 6, ck = idx & 63;
    Wt[(size_t)(nb + rn) * K + kb + ck] = f2bf(t[ck][rn]);
  }
}

// ---------- V transpose: v [b*S+s][g*128+d] bf16 -> Vt [((b*4+g)*128+d)*S + s]
__global__ __launch_bounds__(256) void kvxpose(const u16* __restrict__ v,
                                               u16* __restrict__ vt) {
  __shared__ u16 t[64][66];
  int bg = blockIdx.z;
  int b = bg >> 2, g = bg & 3;
  int s0 = blockIdx.x * 64, d0 = blockIdx.y * 64;
  int tid = threadIdx.x;
  int rr = tid >> 4, cc = (tid & 15) * 4;
#pragma unroll
  for (int it = 0; it < 4; ++it) {
    int r = it * 16 + rr;
    *(uint2*)&t[r][cc] =
        *(const uint2*)(v + (size_t)(b * SEQ + s0 + r) * (NKV * HD) + g * HD + d0 + cc);
  }
  __syncthreads();
#pragma unroll
  for (int it = 0; it < 4; ++it) {
    int r = it * 16 + rr;  // d index within tile
    u16 o[4] = {t[cc][r], t[cc + 1][r], t[cc + 2][r], t[cc + 3][r]};
    *(uint2*)(vt + (size_t)((b * NKV + g) * HD + d0 + r) * SEQ + s0 + cc) = *(const uint2*)o;
  }
}

// ---------- RMSNorm: x [rows][2048] f32 -> out bf16
__global__ __launch_bounds__(256) void krmsnorm(const float* __restrict__ x,
                                                const float* __restrict__ w,
                                                u16* __restrict__ out) {
  int row = blockIdx.x, tid = threadIdx.x;
  const float* xr = x + (size_t)row * DIM;
  float4 a = *(const float4*)(xr + tid * 8);
  float4 b = *(const float4*)(xr + tid * 8 + 4);
  float ss = a.x * a.x + a.y * a.y + a.z * a.z + a.w * a.w +
             b.x * b.x + b.y * b.y + b.z * b.z + b.w * b.w;
#pragma unroll
  for (int off = 1; off < 64; off <<= 1) ss += __shfl_xor(ss, off, 64);
  __shared__ float red[4];
  if ((tid & 63) == 0) red[tid >> 6] = ss;
  __syncthreads();
  float tot = red[0] + red[1] + red[2] + red[3];
  float sc = rsqrtf(tot * (1.0f / DIM) + 1e-5f);
  float xs[8] = {a.x, a.y, a.z, a.w, b.x, b.y, b.z, b.w};
  const float* wr = w + tid * 8;
  u16 o[8];
#pragma unroll
  for (int j = 0; j < 8; ++j) o[j] = f2bf(xs[j] * sc * wr[j]);
  *(int4*)(out + (size_t)row * DIM + tid * 8) = *(const int4*)o;
}

// ---------- RoPE on q (in-place, bf16). one thread per (row, head, pair)
__global__ __launch_bounds__(256) void krope_q(u16* __restrict__ q,
                                               const float* __restrict__ fc) {
  int t = blockIdx.x * 256 + threadIdx.x;           // 2048*16*64 = 2^21
  int j = t & 63;
  int h = (t >> 6) & (NH - 1);
  int row = t >> 10;
  int s = row & (SEQ - 1);
  size_t off = (size_t)row * DIM + h * HD + 2 * j;
  unsigned pk = *(unsigned*)(q + off);
  float x0 = bf2f((u16)pk), x1 = bf2f((u16)(pk >> 16));
  float cs = fc[s * HD + 2 * j], sn = fc[s * HD + 2 * j + 1];
  float y0 = x0 * cs - x1 * sn;
  float y1 = x0 * sn + x1 * cs;
  *(unsigned*)(q + off) = (unsigned)f2bf(y0) | ((unsigned)f2bf(y1) << 16);
}

// ---------- RoPE on k (in-place bf16) + write fp32 cache_k
__global__ __launch_bounds__(256) void krope_k(u16* __restrict__ k,
                                               const float* __restrict__ fc,
                                               float* __restrict__ ck) {
  int t = blockIdx.x * 256 + threadIdx.x;           // 2048*4*64 = 2^19
  int j = t & 63;
  int g = (t >> 6) & (NKV - 1);
  int row = t >> 8;
  int s = row & (SEQ - 1);
  size_t off = (size_t)row * (NKV * HD) + g * HD + 2 * j;
  unsigned pk = *(unsigned*)(k + off);
  float x0 = bf2f((u16)pk), x1 = bf2f((u16)(pk >> 16));
  float cs = fc[s * HD + 2 * j], sn = fc[s * HD + 2 * j + 1];
  float y0 = x0 * cs - x1 * sn;
  float y1 = x0 * sn + x1 * cs;
  *(unsigned*)(k + off) = (unsigned)f2bf(y0) | ((unsigned)f2bf(y1) << 16);
  ck[off] = y0;
  ck[off + 1] = y1;
}

// ---------- GEMM: C[2048][N] = A[2048][K](bf16) * Bt[N][K](bf16)^T
// 2-phase prefetch: double-buffered LDS, per K-step
//   STAGE(next)->compute(cur)->__syncthreads (one barrier/K-step; the 8
//   global_load_lds have the MFMA phase to land before the vmcnt drain).
// XOR-swizzled content (inverse-swizzled global source, swizzled ds_read).
// EPI 0: qkv-route; EPI 2: f32 = acc + res
template <int EPI>
__global__ __launch_bounds__(256) void kgemm(
    const u16* __restrict__ A, const u16* __restrict__ Bt, int N, int K,
    u16* o0, u16* __restrict__ o1, u16* __restrict__ o2,
    float* of, const float* res) {
  __shared__ u16 As[2][128 * 64];
  __shared__ u16 Bs[2][128 * 64];
  int bn = blockIdx.x * 128, bm = blockIdx.y * 128;
  int tid = threadIdx.x, lane = tid & 63, wv = tid >> 6;
  int wm = (wv >> 1) * 64, wn = (wv & 1) * 64;
  int r16 = lane & 15, grp = lane >> 4;
  int srow = lane >> 3;                    // 0..7: row within 8-row chunk
  int schunk = ((lane & 7) ^ srow) * 8;    // inverse-swizzled source k-offset
  f32x4 acc[4][4] = {};
  const u16* Abase = A + (size_t)(bm + wv * 32) * K + schunk;
  const u16* Bbase = Bt + (size_t)(bn + wv * 32) * K + schunk;
  int woff = wv * 32 * 64;

  auto STAGE = [&](int buf, int k0) {
#pragma unroll
    for (int j = 0; j < 4; ++j) {
      gld16(Abase + (size_t)(j * 8 + srow) * K + k0, &As[buf][woff + j * 512]);
      gld16(Bbase + (size_t)(j * 8 + srow) * K + k0, &Bs[buf][woff + j * 512]);
    }
  };
  auto COMPUTE = [&](int buf) {
#pragma unroll
    for (int kk = 0; kk < 2; ++kk) {
      int swz = (((kk << 2) | grp) ^ (r16 & 7)) * 8;
      bf16x8 af[4], bfr[4];
#pragma unroll
      for (int m = 0; m < 4; ++m)
        af[m] = *(const bf16x8*)&As[buf][(wm + m * 16 + r16) * 64 + swz];
#pragma unroll
      for (int n = 0; n < 4; ++n)
        bfr[n] = *(const bf16x8*)&Bs[buf][(wn + n * 16 + r16) * 64 + swz];
#pragma unroll
      for (int m = 0; m < 4; ++m)
#pragma unroll
        for (int n = 0; n < 4; ++n)
          acc[m][n] = __builtin_amdgcn_mfma_f32_16x16x32_bf16(af[m], bfr[n], acc[m][n], 0, 0, 0);
    }
  };

  STAGE(0, 0);
  __syncthreads();
  int nt = K >> 6, cur = 0;
  for (int t = 0; t < nt - 1; ++t) {
    STAGE(cur ^ 1, (t + 1) << 6);
    COMPUTE(cur);
    __syncthreads();
    cur ^= 1;
  }
  COMPUTE(cur);

#pragma unroll
  for (int mi = 0; mi < 4; ++mi) {
#pragma unroll
    for (int ni = 0; ni < 4; ++ni) {
#pragma unroll
      for (int r = 0; r < 4; ++r) {
        int gr = bm + wm + mi * 16 + grp * 4 + r;
        int gc = bn + wn + ni * 16 + r16;
        float v = acc[mi][ni][r];
        if constexpr (EPI == 0) {
          if (gc < DIM) {
            o0[(size_t)gr * DIM + gc] = f2bf(v);
          } else if (gc < DIM + 512) {
            o1[(size_t)gr * 512 + (gc - DIM)] = f2bf(v);
          } else {
            int c2 = gc - (DIM + 512);
            of[(size_t)gr * 512 + c2] = v;
            o2[(size_t)gr * 512 + c2] = f2bf(v);
          }
        } else {
          of[(size_t)gr * N + gc] = v + res[(size_t)gr * N + gc];
        }
      }
    }
  }
}

// ---------- fused gate+up GEMM: out = silu(A@Wg^T) * (A@Wu^T), bf16 [2048][5632]
// shared A-tile, two B-panels, two accumulator sets; same 2-phase prefetch.
__global__ __launch_bounds__(256) void kgemm_gu(
    const u16* __restrict__ A, const u16* __restrict__ Bg, const u16* __restrict__ Bu,
    u16* __restrict__ out) {
  const int N = FFNDIM, K = DIM;
  __shared__ u16 As[2][128 * 64];
  __shared__ u16 Gs[2][128 * 64];
  __shared__ u16 Us[2][128 * 64];
  int bn = blockIdx.x * 128, bm = blockIdx.y * 128;
  int tid = threadIdx.x, lane = tid & 63, wv = tid >> 6;
  int wm = (wv >> 1) * 64, wn = (wv & 1) * 64;
  int r16 = lane & 15, grp = lane >> 4;
  int srow = lane >> 3;
  int schunk = ((lane & 7) ^ srow) * 8;
  f32x4 accg[4][4] = {}, accu[4][4] = {};
  const u16* Abase = A + (size_t)(bm + wv * 32) * K + schunk;
  const u16* Gbase = Bg + (size_t)(bn + wv * 32) * K + schunk;
  const u16* Ubase = Bu + (size_t)(bn + wv * 32) * K + schunk;
  int woff = wv * 32 * 64;

  auto STAGE = [&](int buf, int k0) {
#pragma unroll
    for (int j = 0; j < 4; ++j) {
      gld16(Abase + (size_t)(j * 8 + srow) * K + k0, &As[buf][woff + j * 512]);
      gld16(Gbase + (size_t)(j * 8 + srow) * K + k0, &Gs[buf][woff + j * 512]);
      gld16(Ubase + (size_t)(j * 8 + srow) * K + k0, &Us[buf][woff + j * 512]);
    }
  };
  auto COMPUTE = [&](int buf) {
#pragma unroll
    for (int kk = 0; kk < 2; ++kk) {
      int swz = (((kk << 2) | grp) ^ (r16 & 7)) * 8;
      bf16x8 af[4], gf[4], uf[4];
#pragma unroll
      for (int m = 0; m < 4; ++m)
        af[m] = *(const bf16x8*)&As[buf][(wm + m * 16 + r16) * 64 + swz];
#pragma unroll
      for (int n = 0; n < 4; ++n) {
        gf[n] = *(const bf16x8*)&Gs[buf][(wn + n * 16 + r16) * 64 + swz];
        uf[n] = *(const bf16x8*)&Us[buf][(wn + n * 16 + r16) * 64 + swz];
      }
#pragma unroll
      for (int m = 0; m < 4; ++m)
#pragma unroll
        for (int n = 0; n < 4; ++n) {
          accg[m][n] = __builtin_amdgcn_mfma_f32_16x16x32_bf16(af[m], gf[n], accg[m][n], 0, 0, 0);
          accu[m][n] = __builtin_amdgcn_mfma_f32_16x16x32_bf16(af[m], uf[n], accu[m][n], 0, 0, 0);
        }
    }
  };

  STAGE(0, 0);
  __syncthreads();
  int nt = K >> 6, cur = 0;
  for (int t = 0; t < nt - 1; ++t) {
    STAGE(cur ^ 1, (t + 1) << 6);
    COMPUTE(cur);
    __syncthreads();
    cur ^= 1;
  }
  COMPUTE(cur);

#pragma unroll
  for (int mi = 0; mi < 4; ++mi) {
#pragma unroll
    for (int ni = 0; ni < 4; ++ni) {
#pragma unroll
      for (int r = 0; r < 4; ++r) {
        int gr = bm + wm + mi * 16 + grp * 4 + r;
        int gc = bn + wn + ni * 16 + r16;
        float g = accg[mi][ni][r];
        float sg = g / (1.0f + __expf(-g));
        out[(size_t)gr * N + gc] = f2bf(sg * accu[mi][ni][r]);
      }
    }
  }
}

// ---------- causal GQA flash attention. 1 wave per (b, h, 16 q rows). KV tiles of 32.
// V consumed from pre-transposed Vt[b][g][d][s]: PV B-fragment = one bf16x8 load.
__global__ __launch_bounds__(64) void kattn(const u16* __restrict__ qb,
                                            const u16* __restrict__ kb,
                                            const u16* __restrict__ vtb,
                                            u16* __restrict__ ctxb) {
  __shared__ u16 Plds[16][40];
  int l = threadIdx.x;
  int qt = blockIdx.x, h = blockIdx.y, b = blockIdx.z;
  int g = h >> 2;  // J = NH/NKV = 4
  int q0 = qt * 16;
  int r16 = l & 15, grp = l >> 4;
  const float scale = 0.08838834764831845f;  // 1/sqrt(128)
  bf16x8 qf[4];
  {
    const u16* qrow = qb + (size_t)(b * SEQ + q0 + r16) * DIM + h * HD + grp * 8;
#pragma unroll
    for (int c = 0; c < 4; ++c) qf[c] = *(const bf16x8*)(qrow + c * 32);
  }
  const u16* vt = vtb + (size_t)(b * NKV + g) * HD * SEQ;
  f32x4 ctx[8] = {};
  float m = -1e30f, lsum = 0.0f;
  int q_idx = q0 + r16;
  int ttmax = (q0 + 15) >> 5;
  for (int tt = 0; tt <= ttmax; ++tt) {
    int t0 = tt * 32;
    f32x4 d0 = {0.f, 0.f, 0.f, 0.f}, d1 = {0.f, 0.f, 0.f, 0.f};
    const u16* krow0 = kb + (size_t)(b * SEQ + t0 + r16) * (NKV * HD) + g * HD + grp * 8;
    const u16* krow1 = krow0 + 16 * (NKV * HD);
#pragma unroll
    for (int c = 0; c < 4; ++c) {
      bf16x8 kf0 = *(const bf16x8*)(krow0 + c * 32);
      d0 = __builtin_amdgcn_mfma_f32_16x16x32_bf16(kf0, qf[c], d0, 0, 0, 0);
      bf16x8 kf1 = *(const bf16x8*)(krow1 + c * 32);
      d1 = __builtin_amdgcn_mfma_f32_16x16x32_bf16(kf1, qf[c], d1, 0, 0, 0);
    }
    // lane holds S[q = q0+r16][t = t0 + grp*4 + r (+16)]
    float p[8];
    float mx = -1e30f;
#pragma unroll
    for (int r = 0; r < 4; ++r) {
      int tA = t0 + grp * 4 + r;
      float sA = d0[r] * scale;
      if (tA > q_idx) sA = -1e30f;
      float sB = d1[r] * scale;
      if (tA + 16 > q_idx) sB = -1e30f;
      p[r] = sA; p[r + 4] = sB;
      mx = fmaxf(mx, fmaxf(sA, sB));
    }
    mx = fmaxf(mx, __shfl_xor(mx, 16, 64));
    mx = fmaxf(mx, __shfl_xor(mx, 32, 64));
    float mnew = fmaxf(m, mx);
    float psum = 0.f;
#pragma unroll
    for (int i = 0; i < 8; ++i) { p[i] = __expf(p[i] - mnew); psum += p[i]; }
    psum += __shfl_xor(psum, 16, 64);
    psum += __shfl_xor(psum, 32, 64);
    float corr = __expf(m - mnew);
    lsum = lsum * corr + psum;
    m = mnew;
    // P -> LDS in A-frag-friendly [q][t_rel] layout
    *(unsigned*)&Plds[r16][grp * 4] = (unsigned)f2bf(p[0]) | ((unsigned)f2bf(p[1]) << 16);
    *(unsigned*)&Plds[r16][grp * 4 + 2] = (unsigned)f2bf(p[2]) | ((unsigned)f2bf(p[3]) << 16);
    *(unsigned*)&Plds[r16][16 + grp * 4] = (unsigned)f2bf(p[4]) | ((unsigned)f2bf(p[5]) << 16);
    *(unsigned*)&Plds[r16][16 + grp * 4 + 2] = (unsigned)f2bf(p[6]) | ((unsigned)f2bf(p[7]) << 16);
    // rescale ctx (ctx reg r belongs to q_rel = grp*4+r; corr lives at lane q_rel)
    float cf[4];
#pragma unroll
    for (int r = 0; r < 4; ++r) cf[r] = __shfl(corr, grp * 4 + r, 64);
#pragma unroll
    for (int dc = 0; dc < 8; ++dc)
#pragma unroll
      for (int r = 0; r < 4; ++r) ctx[dc][r] *= cf[r];
    bf16x8 pa;
    {
      union { bf16x8 v; int4 q; } u;
      u.q = *(const int4*)&Plds[r16][grp * 8];
      pa = u.v;
    }
#pragma unroll
    for (int dc = 0; dc < 8; ++dc) {
      bf16x8 vf = *(const bf16x8*)(vt + (size_t)(dc * 16 + r16) * SEQ + t0 + grp * 8);
      ctx[dc] = __builtin_amdgcn_mfma_f32_16x16x32_bf16(pa, vf, ctx[dc], 0, 0, 0);
    }
  }
  float linv = 1.0f / lsum;
  float lf[4];
#pragma unroll
  for (int r = 0; r < 4; ++r) lf[r] = __shfl(linv, grp * 4 + r, 64);
  u16* crow = ctxb + (size_t)(b * SEQ + q0) * DIM + h * HD;
#pragma unroll
  for (int dc = 0; dc < 8; ++dc)
#pragma unroll
    for (int r = 0; r < 4; ++r)
      crow[(size_t)(grp * 4 + r) * DIM + dc * 16 + r16] = f2bf(ctx[dc][r] * lf[r]);
}

extern "C" void kernel_launch(void* const* d_in, const int* in_sizes, int n_in,
                              void* d_out, int out_size, void* d_ws, size_t ws_size,
                              hipStream_t stream) {
  const float* x = (const float*)d_in[0];
  const float* fc = (const float*)d_in[1];
  const float* wq = (const float*)d_in[5];
  const float* wk = (const float*)d_in[6];
  const float* wv = (const float*)d_in[7];
  const float* wo = (const float*)d_in[8];
  const float* wg = (const float*)d_in[9];
  const float* wu = (const float*)d_in[10];
  const float* wd = (const float*)d_in[11];
  const float* anw = (const float*)d_in[12];
  const float* fnw = (const float*)d_in[13];

  float* out_x = (float*)d_out;                       // [2048][2048] f32
  float* out_ck = out_x + (size_t)MROWS * DIM;        // [2048][512] f32
  float* out_cv = out_ck + (size_t)MROWS * NKV * HD;  // [2048][512] f32

  char* ws = (char*)d_ws;
  u16* h_b   = (u16*)(ws);                      // 8 MB   [2048][2048] bf16
  u16* q_b   = (u16*)(ws + (8u << 20));         // 8 MB   [2048][2048]
  u16* k_b   = (u16*)(ws + (16u << 20));        // 2 MB   [2048][512]
  u16* v_b   = (u16*)(ws + (18u << 20));        // 2 MB   [2048][512]
  u16* ctx_b = (u16*)(ws + (20u << 20));        // 8 MB   [2048][2048]
  u16* hf_b  = (u16*)(ws + (28u << 20));        // 8 MB   [2048][2048]
  u16* g_b   = (u16*)(ws + (36u << 20));        // 23 MB  [2048][5632] silu(g)*u
  u16* Wt    = (u16*)(ws + (60u << 20));        // 23 MB  transposed bf16 weights
  u16* vt_b  = h_b;       // reuse: h_b dead after QKV GEMM (2 MB)
  u16* wg_t  = (u16*)ws;  // reuse ws[0,23MB): h/q/k/v/ctx all dead post-proj

  // QKV weights -> Wt rows [0,2048)=wq^T, [2048,2560)=wk^T, [2560,3072)=wv^T
  kxpose<<<dim3(2048 / 64, 2048 / 64), 256, 0, stream>>>(wq, Wt, 2048, 2048);
  kxpose<<<dim3(512 / 64, 2048 / 64), 256, 0, stream>>>(wk, Wt + (size_t)2048 * 2048, 2048, 512);
  kxpose<<<dim3(512 / 64, 2048 / 64), 256, 0, stream>>>(wv, Wt + (size_t)2560 * 2048, 2048, 512);

  krmsnorm<<<MROWS, 256, 0, stream>>>(x, anw, h_b);
  kgemm<0><<<dim3(3072 / 128, 16), 256, 0, stream>>>(h_b, Wt, 3072, 2048,
                                                     q_b, k_b, v_b, out_cv, nullptr);
  krope_q<<<8192, 256, 0, stream>>>(q_b, fc);
  krope_k<<<2048, 256, 0, stream>>>(k_b, fc, out_ck);
  kvxpose<<<dim3(SEQ / 64, HD / 64, BSZ * NKV), 256, 0, stream>>>(v_b, vt_b);
  kattn<<<dim3(SEQ / 16, NH, BSZ), 64, 0, stream>>>(q_b, k_b, vt_b, ctx_b);

  kxpose<<<dim3(32, 32), 256, 0, stream>>>(wo, Wt, 2048, 2048);
  kgemm<2><<<dim3(16, 16), 256, 0, stream>>>(ctx_b, Wt, 2048, 2048,
                                             nullptr, nullptr, nullptr, out_x, x);
  krmsnorm<<<MROWS, 256, 0, stream>>>(out_x, fnw, hf_b);

  // FFN: fused gate+up (wg^T into dead front region, wu^T into Wt)
  kxpose<<<dim3(5632 / 64, 2048 / 64), 256, 0, stream>>>(wg, wg_t, 2048, 5632);
  kxpose<<<dim3(5632 / 64, 2048 / 64), 256, 0, stream>>>(wu, Wt, 2048, 5632);
  kgemm_gu<<<dim3(5632 / 128, 16), 256, 0, stream>>>(hf_b, wg_t, Wt, g_b);
  kxpose<<<dim3(2048 / 64, 5632 / 64), 256, 0, stream>>>(wd, Wt, 5632, 2048);
  kgemm<2><<<dim3(16, 16), 256, 0, stream>>>(g_b, Wt, 2048, 5632,
                                             nullptr, nullptr, nullptr, out_x, out_x);
}

// Round 5
// 545.519 us; speedup vs baseline: 1.0713x; 1.0713x over previous
//
#include <hip/hip_runtime.h>

typedef float f32x4 __attribute__((ext_vector_type(4)));
typedef __bf16 bf16x8 __attribute__((ext_vector_type(8)));
typedef unsigned short u16;

#define DIM 2048
#define SEQ 1024
#define BSZ 2
#define NH 16
#define NKV 4
#define HD 128
#define FFNDIM 5632
#define MROWS (BSZ * SEQ)  // 2048

__device__ __forceinline__ u16 f2bf(float f) {
  union { float f; unsigned u; } v; v.f = f;
  unsigned u = v.u;
  unsigned r = (u + 0x7fffu + ((u >> 16) & 1u)) >> 16;  // RNE
  return (u16)r;
}
__device__ __forceinline__ float bf2f(u16 h) {
  union { unsigned u; float f; } v; v.u = ((unsigned)h) << 16; return v.f;
}

__device__ __forceinline__ void gld16(const void* g, void* l) {
  __builtin_amdgcn_global_load_lds(
      (const __attribute__((address_space(1))) unsigned int*)g,
      (__attribute__((address_space(3))) unsigned int*)l, 16, 0, 0);
}

// ---------- transpose + fp32->bf16 convert: W [K][N] f32  ->  Wt [N][K] bf16
__global__ __launch_bounds__(256) void kxpose(const float* __restrict__ W,
                                              u16* __restrict__ Wt,
                                              int K, int N) {
  __shared__ float t[64][65];
  int kb = blockIdx.y * 64, nb = blockIdx.x * 64;
  int tid = threadIdx.x;
#pragma unroll
  for (int it = 0; it < 16; ++it) {
    int idx = it * 256 + tid;
    int r = idx >> 6, c = idx & 63;
    t[r][c] = W[(size_t)(kb + r) * N + nb + c];
  }
  __syncthreads();
#pragma unroll
  for (int it = 0; it < 16; ++it) {
    int idx = it * 256 + tid;
    int rn = idx >> 6, ck = idx & 63;
    Wt[(size_t)(nb + rn) * K + kb + ck] = f2bf(t[ck][rn]);
  }
}

// ---------- V transpose: v [b*S+s][g*128+d] bf16 -> Vt [((b*4+g)*128+d)*S + s]
__global__ __launch_bounds__(256) void kvxpose(const u16* __restrict__ v,
                                               u16* __restrict__ vt) {
  __shared__ u16 t[64][66];
  int bg = blockIdx.z;
  int b = bg >> 2, g = bg & 3;
  int s0 = blockIdx.x * 64, d0 = blockIdx.y * 64;
  int tid = threadIdx.x;
  int rr = tid >> 4, cc = (tid & 15) * 4;
#pragma unroll
  for (int it = 0; it < 4; ++it) {
    int r = it * 16 + rr;
    *(uint2*)&t[r][cc] =
        *(const uint2*)(v + (size_t)(b * SEQ + s0 + r) * (NKV * HD) + g * HD + d0 + cc);
  }
  __syncthreads();
#pragma unroll
  for (int it = 0; it < 4; ++it) {
    int r = it * 16 + rr;  // d index within tile
    u16 o[4] = {t[cc][r], t[cc + 1][r], t[cc + 2][r], t[cc + 3][r]};
    *(uint2*)(vt + (size_t)((b * NKV + g) * HD + d0 + r) * SEQ + s0 + cc) = *(const uint2*)o;
  }
}

// ---------- RMSNorm: x [rows][2048] f32 -> out bf16
__global__ __launch_bounds__(256) void krmsnorm(const float* __restrict__ x,
                                                const float* __restrict__ w,
                                                u16* __restrict__ out) {
  int row = blockIdx.x, tid = threadIdx.x;
  const float* xr = x + (size_t)row * DIM;
  float4 a = *(const float4*)(xr + tid * 8);
  float4 b = *(const float4*)(xr + tid * 8 + 4);
  float ss = a.x * a.x + a.y * a.y + a.z * a.z + a.w * a.w +
             b.x * b.x + b.y * b.y + b.z * b.z + b.w * b.w;
#pragma unroll
  for (int off = 1; off < 64; off <<= 1) ss += __shfl_xor(ss, off, 64);
  __shared__ float red[4];
  if ((tid & 63) == 0) red[tid >> 6] = ss;
  __syncthreads();
  float tot = red[0] + red[1] + red[2] + red[3];
  float sc = rsqrtf(tot * (1.0f / DIM) + 1e-5f);
  float xs[8] = {a.x, a.y, a.z, a.w, b.x, b.y, b.z, b.w};
  const float* wr = w + tid * 8;
  u16 o[8];
#pragma unroll
  for (int j = 0; j < 8; ++j) o[j] = f2bf(xs[j] * sc * wr[j]);
  *(int4*)(out + (size_t)row * DIM + tid * 8) = *(const int4*)o;
}

// ---------- RoPE on q (in-place, bf16). one thread per (row, head, pair)
__global__ __launch_bounds__(256) void krope_q(u16* __restrict__ q,
                                               const float* __restrict__ fc) {
  int t = blockIdx.x * 256 + threadIdx.x;           // 2048*16*64 = 2^21
  int j = t & 63;
  int h = (t >> 6) & (NH - 1);
  int row = t >> 10;
  int s = row & (SEQ - 1);
  size_t off = (size_t)row * DIM + h * HD + 2 * j;
  unsigned pk = *(unsigned*)(q + off);
  float x0 = bf2f((u16)pk), x1 = bf2f((u16)(pk >> 16));
  float cs = fc[s * HD + 2 * j], sn = fc[s * HD + 2 * j + 1];
  float y0 = x0 * cs - x1 * sn;
  float y1 = x0 * sn + x1 * cs;
  *(unsigned*)(q + off) = (unsigned)f2bf(y0) | ((unsigned)f2bf(y1) << 16);
}

// ---------- RoPE on k (in-place bf16) + write fp32 cache_k
__global__ __launch_bounds__(256) void krope_k(u16* __restrict__ k,
                                               const float* __restrict__ fc,
                                               float* __restrict__ ck) {
  int t = blockIdx.x * 256 + threadIdx.x;           // 2048*4*64 = 2^19
  int j = t & 63;
  int g = (t >> 6) & (NKV - 1);
  int row = t >> 8;
  int s = row & (SEQ - 1);
  size_t off = (size_t)row * (NKV * HD) + g * HD + 2 * j;
  unsigned pk = *(unsigned*)(k + off);
  float x0 = bf2f((u16)pk), x1 = bf2f((u16)(pk >> 16));
  float cs = fc[s * HD + 2 * j], sn = fc[s * HD + 2 * j + 1];
  float y0 = x0 * cs - x1 * sn;
  float y1 = x0 * sn + x1 * cs;
  *(unsigned*)(k + off) = (unsigned)f2bf(y0) | ((unsigned)f2bf(y1) << 16);
  ck[off] = y0;
  ck[off + 1] = y1;
}

// ---------- GEMM: C[2048][N] = A[2048][K](bf16) * Bt[N][K](bf16)^T
// Counted-vmcnt pipeline (T4): dbuf LDS; per K-step issue next-tile
// global_load_lds, then s_waitcnt vmcnt(8) (prev tile landed, new 8 stay in
// flight ACROSS the raw s_barrier), sched_barrier pin, compute, release
// barrier. XOR-swizzled LDS content (inverse-swizzled source + swizzled read).
// EPI 0: qkv-route; EPI 2: f32 = acc + res
template <int EPI>
__global__ __launch_bounds__(256) void kgemm(
    const u16* __restrict__ A, const u16* __restrict__ Bt, int N, int K,
    u16* o0, u16* __restrict__ o1, u16* __restrict__ o2,
    float* of, const float* res) {
  __shared__ u16 As[2][128 * 64];
  __shared__ u16 Bs[2][128 * 64];
  int bn = blockIdx.x * 128, bm = blockIdx.y * 128;
  int tid = threadIdx.x, lane = tid & 63, wv = tid >> 6;
  int wm = (wv >> 1) * 64, wn = (wv & 1) * 64;
  int r16 = lane & 15, grp = lane >> 4;
  int srow = lane >> 3;                    // 0..7: row within 8-row chunk
  int schunk = ((lane & 7) ^ srow) * 8;    // inverse-swizzled source k-offset
  f32x4 acc[4][4] = {};
  const u16* Abase = A + (size_t)(bm + wv * 32) * K + schunk;
  const u16* Bbase = Bt + (size_t)(bn + wv * 32) * K + schunk;
  int woff = wv * 32 * 64;

  auto STAGE = [&](int buf, int k0) {
#pragma unroll
    for (int j = 0; j < 4; ++j) {
      gld16(Abase + (size_t)(j * 8 + srow) * K + k0, &As[buf][woff + j * 512]);
      gld16(Bbase + (size_t)(j * 8 + srow) * K + k0, &Bs[buf][woff + j * 512]);
    }
  };
  auto COMPUTE = [&](int buf) {
#pragma unroll
    for (int kk = 0; kk < 2; ++kk) {
      int swz = (((kk << 2) | grp) ^ (r16 & 7)) * 8;
      bf16x8 af[4], bfr[4];
#pragma unroll
      for (int m = 0; m < 4; ++m)
        af[m] = *(const bf16x8*)&As[buf][(wm + m * 16 + r16) * 64 + swz];
#pragma unroll
      for (int n = 0; n < 4; ++n)
        bfr[n] = *(const bf16x8*)&Bs[buf][(wn + n * 16 + r16) * 64 + swz];
#pragma unroll
      for (int m = 0; m < 4; ++m)
#pragma unroll
        for (int n = 0; n < 4; ++n)
          acc[m][n] = __builtin_amdgcn_mfma_f32_16x16x32_bf16(af[m], bfr[n], acc[m][n], 0, 0, 0);
    }
  };

  STAGE(0, 0);
  int nt = K >> 6;
  for (int t = 0; t < nt; ++t) {
    int cur = t & 1;
    if (t + 1 < nt) {
      STAGE(cur ^ 1, (t + 1) << 6);
      asm volatile("s_waitcnt vmcnt(8)" ::: "memory");
    } else {
      asm volatile("s_waitcnt vmcnt(0)" ::: "memory");
    }
    __builtin_amdgcn_sched_barrier(0);
    __builtin_amdgcn_s_barrier();   // tile t visible to all waves
    __builtin_amdgcn_sched_barrier(0);
    COMPUTE(cur);
    __builtin_amdgcn_s_barrier();   // all waves done reading buf[cur]
  }

#pragma unroll
  for (int mi = 0; mi < 4; ++mi) {
#pragma unroll
    for (int ni = 0; ni < 4; ++ni) {
#pragma unroll
      for (int r = 0; r < 4; ++r) {
        int gr = bm + wm + mi * 16 + grp * 4 + r;
        int gc = bn + wn + ni * 16 + r16;
        float v = acc[mi][ni][r];
        if constexpr (EPI == 0) {
          if (gc < DIM) {
            o0[(size_t)gr * DIM + gc] = f2bf(v);
          } else if (gc < DIM + 512) {
            o1[(size_t)gr * 512 + (gc - DIM)] = f2bf(v);
          } else {
            int c2 = gc - (DIM + 512);
            of[(size_t)gr * 512 + c2] = v;
            o2[(size_t)gr * 512 + c2] = f2bf(v);
          }
        } else {
          of[(size_t)gr * N + gc] = v + res[(size_t)gr * N + gc];
        }
      }
    }
  }
}

// ---------- fused gate+up GEMM: out = silu(A@Wg^T) * (A@Wu^T), bf16 [2048][5632]
// shared A-tile, two B-panels, two accumulator sets; counted-vmcnt pipeline.
__global__ __launch_bounds__(256) void kgemm_gu(
    const u16* __restrict__ A, const u16* __restrict__ Bg, const u16* __restrict__ Bu,
    u16* __restrict__ out) {
  const int N = FFNDIM, K = DIM;
  __shared__ u16 As[2][128 * 64];
  __shared__ u16 Gs[2][128 * 64];
  __shared__ u16 Us[2][128 * 64];
  int bn = blockIdx.x * 128, bm = blockIdx.y * 128;
  int tid = threadIdx.x, lane = tid & 63, wv = tid >> 6;
  int wm = (wv >> 1) * 64, wn = (wv & 1) * 64;
  int r16 = lane & 15, grp = lane >> 4;
  int srow = lane >> 3;
  int schunk = ((lane & 7) ^ srow) * 8;
  f32x4 accg[4][4] = {}, accu[4][4] = {};
  const u16* Abase = A + (size_t)(bm + wv * 32) * K + schunk;
  const u16* Gbase = Bg + (size_t)(bn + wv * 32) * K + schunk;
  const u16* Ubase = Bu + (size_t)(bn + wv * 32) * K + schunk;
  int woff = wv * 32 * 64;

  auto STAGE = [&](int buf, int k0) {
#pragma unroll
    for (int j = 0; j < 4; ++j) {
      gld16(Abase + (size_t)(j * 8 + srow) * K + k0, &As[buf][woff + j * 512]);
      gld16(Gbase + (size_t)(j * 8 + srow) * K + k0, &Gs[buf][woff + j * 512]);
      gld16(Ubase + (size_t)(j * 8 + srow) * K + k0, &Us[buf][woff + j * 512]);
    }
  };
  auto COMPUTE = [&](int buf) {
#pragma unroll
    for (int kk = 0; kk < 2; ++kk) {
      int swz = (((kk << 2) | grp) ^ (r16 & 7)) * 8;
      bf16x8 af[4], gf[4], uf[4];
#pragma unroll
      for (int m = 0; m < 4; ++m)
        af[m] = *(const bf16x8*)&As[buf][(wm + m * 16 + r16) * 64 + swz];
#pragma unroll
      for (int n = 0; n < 4; ++n) {
        gf[n] = *(const bf16x8*)&Gs[buf][(wn + n * 16 + r16) * 64 + swz];
        uf[n] = *(const bf16x8*)&Us[buf][(wn + n * 16 + r16) * 64 + swz];
      }
#pragma unroll
      for (int m = 0; m < 4; ++m)
#pragma unroll
        for (int n = 0; n < 4; ++n) {
          accg[m][n] = __builtin_amdgcn_mfma_f32_16x16x32_bf16(af[m], gf[n], accg[m][n], 0, 0, 0);
          accu[m][n] = __builtin_amdgcn_mfma_f32_16x16x32_bf16(af[m], uf[n], accu[m][n], 0, 0, 0);
        }
    }
  };

  STAGE(0, 0);
  int nt = K >> 6;
  for (int t = 0; t < nt; ++t) {
    int cur = t & 1;
    if (t + 1 < nt) {
      STAGE(cur ^ 1, (t + 1) << 6);
      asm volatile("s_waitcnt vmcnt(12)" ::: "memory");
    } else {
      asm volatile("s_waitcnt vmcnt(0)" ::: "memory");
    }
    __builtin_amdgcn_sched_barrier(0);
    __builtin_amdgcn_s_barrier();
    __builtin_amdgcn_sched_barrier(0);
    COMPUTE(cur);
    __builtin_amdgcn_s_barrier();
  }

#pragma unroll
  for (int mi = 0; mi < 4; ++mi) {
#pragma unroll
    for (int ni = 0; ni < 4; ++ni) {
#pragma unroll
      for (int r = 0; r < 4; ++r) {
        int gr = bm + wm + mi * 16 + grp * 4 + r;
        int gc = bn + wn + ni * 16 + r16;
        float g = accg[mi][ni][r];
        float sg = g / (1.0f + __expf(-g));
        out[(size_t)gr * N + gc] = f2bf(sg * accu[mi][ni][r]);
      }
    }
  }
}

// ---------- causal GQA flash attention. 1 wave per (b, h, 16 q rows). KV tiles of 32.
// V consumed from pre-transposed Vt[b][g][d][s]: PV B-fragment = one bf16x8 load.
__global__ __launch_bounds__(64) void kattn(const u16* __restrict__ qb,
                                            const u16* __restrict__ kb,
                                            const u16* __restrict__ vtb,
                                            u16* __restrict__ ctxb) {
  __shared__ u16 Plds[16][40];
  int l = threadIdx.x;
  int qt = blockIdx.x, h = blockIdx.y, b = blockIdx.z;
  int g = h >> 2;  // J = NH/NKV = 4
  int q0 = qt * 16;
  int r16 = l & 15, grp = l >> 4;
  const float scale = 0.08838834764831845f;  // 1/sqrt(128)
  bf16x8 qf[4];
  {
    const u16* qrow = qb + (size_t)(b * SEQ + q0 + r16) * DIM + h * HD + grp * 8;
#pragma unroll
    for (int c = 0; c < 4; ++c) qf[c] = *(const bf16x8*)(qrow + c * 32);
  }
  const u16* vt = vtb + (size_t)(b * NKV + g) * HD * SEQ;
  f32x4 ctx[8] = {};
  float m = -1e30f, lsum = 0.0f;
  int q_idx = q0 + r16;
  int ttmax = (q0 + 15) >> 5;
  for (int tt = 0; tt <= ttmax; ++tt) {
    int t0 = tt * 32;
    f32x4 d0 = {0.f, 0.f, 0.f, 0.f}, d1 = {0.f, 0.f, 0.f, 0.f};
    const u16* krow0 = kb + (size_t)(b * SEQ + t0 + r16) * (NKV * HD) + g * HD + grp * 8;
    const u16* krow1 = krow0 + 16 * (NKV * HD);
#pragma unroll
    for (int c = 0; c < 4; ++c) {
      bf16x8 kf0 = *(const bf16x8*)(krow0 + c * 32);
      d0 = __builtin_amdgcn_mfma_f32_16x16x32_bf16(kf0, qf[c], d0, 0, 0, 0);
      bf16x8 kf1 = *(const bf16x8*)(krow1 + c * 32);
      d1 = __builtin_amdgcn_mfma_f32_16x16x32_bf16(kf1, qf[c], d1, 0, 0, 0);
    }
    // lane holds S[q = q0+r16][t = t0 + grp*4 + r (+16)]
    float p[8];
    float mx = -1e30f;
#pragma unroll
    for (int r = 0; r < 4; ++r) {
      int tA = t0 + grp * 4 + r;
      float sA = d0[r] * scale;
      if (tA > q_idx) sA = -1e30f;
      float sB = d1[r] * scale;
      if (tA + 16 > q_idx) sB = -1e30f;
      p[r] = sA; p[r + 4] = sB;
      mx = fmaxf(mx, fmaxf(sA, sB));
    }
    mx = fmaxf(mx, __shfl_xor(mx, 16, 64));
    mx = fmaxf(mx, __shfl_xor(mx, 32, 64));
    float mnew = fmaxf(m, mx);
    float psum = 0.f;
#pragma unroll
    for (int i = 0; i < 8; ++i) { p[i] = __expf(p[i] - mnew); psum += p[i]; }
    psum += __shfl_xor(psum, 16, 64);
    psum += __shfl_xor(psum, 32, 64);
    float corr = __expf(m - mnew);
    lsum = lsum * corr + psum;
    m = mnew;
    // P -> LDS in A-frag-friendly [q][t_rel] layout
    *(unsigned*)&Plds[r16][grp * 4] = (unsigned)f2bf(p[0]) | ((unsigned)f2bf(p[1]) << 16);
    *(unsigned*)&Plds[r16][grp * 4 + 2] = (unsigned)f2bf(p[2]) | ((unsigned)f2bf(p[3]) << 16);
    *(unsigned*)&Plds[r16][16 + grp * 4] = (unsigned)f2bf(p[4]) | ((unsigned)f2bf(p[5]) << 16);
    *(unsigned*)&Plds[r16][16 + grp * 4 + 2] = (unsigned)f2bf(p[6]) | ((unsigned)f2bf(p[7]) << 16);
    // rescale ctx (ctx reg r belongs to q_rel = grp*4+r; corr lives at lane q_rel)
    float cf[4];
#pragma unroll
    for (int r = 0; r < 4; ++r) cf[r] = __shfl(corr, grp * 4 + r, 64);
#pragma unroll
    for (int dc = 0; dc < 8; ++dc)
#pragma unroll
      for (int r = 0; r < 4; ++r) ctx[dc][r] *= cf[r];
    bf16x8 pa;
    {
      union { bf16x8 v; int4 q; } u;
      u.q = *(const int4*)&Plds[r16][grp * 8];
      pa = u.v;
    }
#pragma unroll
    for (int dc = 0; dc < 8; ++dc) {
      bf16x8 vf = *(const bf16x8*)(vt + (size_t)(dc * 16 + r16) * SEQ + t0 + grp * 8);
      ctx[dc] = __builtin_amdgcn_mfma_f32_16x16x32_bf16(pa, vf, ctx[dc], 0, 0, 0);
    }
  }
  float linv = 1.0f / lsum;
  float lf[4];
#pragma unroll
  for (int r = 0; r < 4; ++r) lf[r] = __shfl(linv, grp * 4 + r, 64);
  u16* crow = ctxb + (size_t)(b * SEQ + q0) * DIM + h * HD;
#pragma unroll
  for (int dc = 0; dc < 8; ++dc)
#pragma unroll
    for (int r = 0; r < 4; ++r)
      crow[(size_t)(grp * 4 + r) * DIM + dc * 16 + r16] = f2bf(ctx[dc][r] * lf[r]);
}

extern "C" void kernel_launch(void* const* d_in, const int* in_sizes, int n_in,
                              void* d_out, int out_size, void* d_ws, size_t ws_size,
                              hipStream_t stream) {
  const float* x = (const float*)d_in[0];
  const float* fc = (const float*)d_in[1];
  const float* wq = (const float*)d_in[5];
  const float* wk = (const float*)d_in[6];
  const float* wv = (const float*)d_in[7];
  const float* wo = (const float*)d_in[8];
  const float* wg = (const float*)d_in[9];
  const float* wu = (const float*)d_in[10];
  const float* wd = (const float*)d_in[11];
  const float* anw = (const float*)d_in[12];
  const float* fnw = (const float*)d_in[13];

  float* out_x = (float*)d_out;                       // [2048][2048] f32
  float* out_ck = out_x + (size_t)MROWS * DIM;        // [2048][512] f32
  float* out_cv = out_ck + (size_t)MROWS * NKV * HD;  // [2048][512] f32

  char* ws = (char*)d_ws;
  u16* h_b   = (u16*)(ws);                      // 8 MB   [2048][2048] bf16
  u16* q_b   = (u16*)(ws + (8u << 20));         // 8 MB   [2048][2048]
  u16* k_b   = (u16*)(ws + (16u << 20));        // 2 MB   [2048][512]
  u16* v_b   = (u16*)(ws + (18u << 20));        // 2 MB   [2048][512]
  u16* ctx_b = (u16*)(ws + (20u << 20));        // 8 MB   [2048][2048]
  u16* hf_b  = (u16*)(ws + (28u << 20));        // 8 MB   [2048][2048]
  u16* g_b   = (u16*)(ws + (36u << 20));        // 23 MB  [2048][5632] silu(g)*u
  u16* Wt    = (u16*)(ws + (60u << 20));        // 23 MB  transposed bf16 weights
  u16* vt_b  = h_b;       // reuse: h_b dead after QKV GEMM (2 MB)
  u16* wg_t  = (u16*)ws;  // reuse ws[0,23MB): h/q/k/v/ctx all dead post-proj

  // QKV weights -> Wt rows [0,2048)=wq^T, [2048,2560)=wk^T, [2560,3072)=wv^T
  kxpose<<<dim3(2048 / 64, 2048 / 64), 256, 0, stream>>>(wq, Wt, 2048, 2048);
  kxpose<<<dim3(512 / 64, 2048 / 64), 256, 0, stream>>>(wk, Wt + (size_t)2048 * 2048, 2048, 512);
  kxpose<<<dim3(512 / 64, 2048 / 64), 256, 0, stream>>>(wv, Wt + (size_t)2560 * 2048, 2048, 512);

  krmsnorm<<<MROWS, 256, 0, stream>>>(x, anw, h_b);
  kgemm<0><<<dim3(3072 / 128, 16), 256, 0, stream>>>(h_b, Wt, 3072, 2048,
                                                     q_b, k_b, v_b, out_cv, nullptr);
  krope_q<<<8192, 256, 0, stream>>>(q_b, fc);
  krope_k<<<2048, 256, 0, stream>>>(k_b, fc, out_ck);
  kvxpose<<<dim3(SEQ / 64, HD / 64, BSZ * NKV), 256, 0, stream>>>(v_b, vt_b);
  kattn<<<dim3(SEQ / 16, NH, BSZ), 64, 0, stream>>>(q_b, k_b, vt_b, ctx_b);

  kxpose<<<dim3(32, 32), 256, 0, stream>>>(wo, Wt, 2048, 2048);
  kgemm<2><<<dim3(16, 16), 256, 0, stream>>>(ctx_b, Wt, 2048, 2048,
                                             nullptr, nullptr, nullptr, out_x, x);
  krmsnorm<<<MROWS, 256, 0, stream>>>(out_x, fnw, hf_b);

  // FFN: fused gate+up (wg^T into dead front region, wu^T into Wt)
  kxpose<<<dim3(5632 / 64, 2048 / 64), 256, 0, stream>>>(wg, wg_t, 2048, 5632);
  kxpose<<<dim3(5632 / 64, 2048 / 64), 256, 0, stream>>>(wu, Wt, 2048, 5632);
  kgemm_gu<<<dim3(5632 / 128, 16), 256, 0, stream>>>(hf_b, wg_t, Wt, g_b);
  kxpose<<<dim3(2048 / 64, 5632 / 64), 256, 0, stream>>>(wd, Wt, 5632, 2048);
  kgemm<2><<<dim3(16, 16), 256, 0, stream>>>(g_b, Wt, 2048, 5632,
                                             nullptr, nullptr, nullptr, out_x, out_x);
}

// Round 6
// 523.762 us; speedup vs baseline: 1.1158x; 1.0415x over previous
//
#include <hip/hip_runtime.h>

typedef float f32x4 __attribute__((ext_vector_type(4)));
typedef __bf16 bf16x8 __attribute__((ext_vector_type(8)));
typedef unsigned short u16;

#define DIM 2048
#define SEQ 1024
#define BSZ 2
#define NH 16
#define NKV 4
#define HD 128
#define FFNDIM 5632
#define MROWS (BSZ * SEQ)  // 2048

__device__ __forceinline__ u16 f2bf(float f) {
  union { float f; unsigned u; } v; v.f = f;
  unsigned u = v.u;
  unsigned r = (u + 0x7fffu + ((u >> 16) & 1u)) >> 16;  // RNE
  return (u16)r;
}
__device__ __forceinline__ float bf2f(u16 h) {
  union { unsigned u; float f; } v; v.u = ((unsigned)h) << 16; return v.f;
}

__device__ __forceinline__ void gld16(const void* g, void* l) {
  __builtin_amdgcn_global_load_lds(
      (const __attribute__((address_space(1))) unsigned int*)g,
      (__attribute__((address_space(3))) unsigned int*)l, 16, 0, 0);
}

// ---------- transpose + fp32->bf16 convert: W [K][N] f32 -> Wt[(n*rs+ro)][K] bf16
__global__ __launch_bounds__(256) void kxpose(const float* __restrict__ W,
                                              u16* __restrict__ Wt,
                                              int K, int N, int rs, int ro) {
  __shared__ float t[64][65];
  int kb = blockIdx.y * 64, nb = blockIdx.x * 64;
  int tid = threadIdx.x;
#pragma unroll
  for (int it = 0; it < 16; ++it) {
    int idx = it * 256 + tid;
    int r = idx >> 6, c = idx & 63;
    t[r][c] = W[(size_t)(kb + r) * N + nb + c];
  }
  __syncthreads();
#pragma unroll
  for (int it = 0; it < 16; ++it) {
    int idx = it * 256 + tid;
    int rn = idx >> 6, ck = idx & 63;
    Wt[((size_t)(nb + rn) * rs + ro) * K + kb + ck] = f2bf(t[ck][rn]);
  }
}

// ---------- V transpose: v [b*S+s][g*128+d] bf16 -> Vt [((b*4+g)*128+d)*S + s]
__global__ __launch_bounds__(256) void kvxpose(const u16* __restrict__ v,
                                               u16* __restrict__ vt) {
  __shared__ u16 t[64][66];
  int bg = blockIdx.z;
  int b = bg >> 2, g = bg & 3;
  int s0 = blockIdx.x * 64, d0 = blockIdx.y * 64;
  int tid = threadIdx.x;
  int rr = tid >> 4, cc = (tid & 15) * 4;
#pragma unroll
  for (int it = 0; it < 4; ++it) {
    int r = it * 16 + rr;
    *(uint2*)&t[r][cc] =
        *(const uint2*)(v + (size_t)(b * SEQ + s0 + r) * (NKV * HD) + g * HD + d0 + cc);
  }
  __syncthreads();
#pragma unroll
  for (int it = 0; it < 4; ++it) {
    int r = it * 16 + rr;  // d index within tile
    u16 o[4] = {t[cc][r], t[cc + 1][r], t[cc + 2][r], t[cc + 3][r]};
    *(uint2*)(vt + (size_t)((b * NKV + g) * HD + d0 + r) * SEQ + s0 + cc) = *(const uint2*)o;
  }
}

// ---------- RMSNorm: x [rows][2048] f32 -> out bf16
__global__ __launch_bounds__(256) void krmsnorm(const float* __restrict__ x,
                                                const float* __restrict__ w,
                                                u16* __restrict__ out) {
  int row = blockIdx.x, tid = threadIdx.x;
  const float* xr = x + (size_t)row * DIM;
  float4 a = *(const float4*)(xr + tid * 8);
  float4 b = *(const float4*)(xr + tid * 8 + 4);
  float ss = a.x * a.x + a.y * a.y + a.z * a.z + a.w * a.w +
             b.x * b.x + b.y * b.y + b.z * b.z + b.w * b.w;
#pragma unroll
  for (int off = 1; off < 64; off <<= 1) ss += __shfl_xor(ss, off, 64);
  __shared__ float red[4];
  if ((tid & 63) == 0) red[tid >> 6] = ss;
  __syncthreads();
  float tot = red[0] + red[1] + red[2] + red[3];
  float sc = rsqrtf(tot * (1.0f / DIM) + 1e-5f);
  float xs[8] = {a.x, a.y, a.z, a.w, b.x, b.y, b.z, b.w};
  const float* wr = w + tid * 8;
  u16 o[8];
#pragma unroll
  for (int j = 0; j < 8; ++j) o[j] = f2bf(xs[j] * sc * wr[j]);
  *(int4*)(out + (size_t)row * DIM + tid * 8) = *(const int4*)o;
}

// ---------- RoPE on q (in-place, bf16). one thread per (row, head, pair)
__global__ __launch_bounds__(256) void krope_q(u16* __restrict__ q,
                                               const float* __restrict__ fc) {
  int t = blockIdx.x * 256 + threadIdx.x;           // 2048*16*64 = 2^21
  int j = t & 63;
  int h = (t >> 6) & (NH - 1);
  int row = t >> 10;
  int s = row & (SEQ - 1);
  size_t off = (size_t)row * DIM + h * HD + 2 * j;
  unsigned pk = *(unsigned*)(q + off);
  float x0 = bf2f((u16)pk), x1 = bf2f((u16)(pk >> 16));
  float cs = fc[s * HD + 2 * j], sn = fc[s * HD + 2 * j + 1];
  float y0 = x0 * cs - x1 * sn;
  float y1 = x0 * sn + x1 * cs;
  *(unsigned*)(q + off) = (unsigned)f2bf(y0) | ((unsigned)f2bf(y1) << 16);
}

// ---------- RoPE on k (in-place bf16) + write fp32 cache_k
__global__ __launch_bounds__(256) void krope_k(u16* __restrict__ k,
                                               const float* __restrict__ fc,
                                               float* __restrict__ ck) {
  int t = blockIdx.x * 256 + threadIdx.x;           // 2048*4*64 = 2^19
  int j = t & 63;
  int g = (t >> 6) & (NKV - 1);
  int row = t >> 8;
  int s = row & (SEQ - 1);
  size_t off = (size_t)row * (NKV * HD) + g * HD + 2 * j;
  unsigned pk = *(unsigned*)(k + off);
  float x0 = bf2f((u16)pk), x1 = bf2f((u16)(pk >> 16));
  float cs = fc[s * HD + 2 * j], sn = fc[s * HD + 2 * j + 1];
  float y0 = x0 * cs - x1 * sn;
  float y1 = x0 * sn + x1 * cs;
  *(unsigned*)(k + off) = (unsigned)f2bf(y0) | ((unsigned)f2bf(y1) << 16);
  ck[off] = y0;
  ck[off + 1] = y1;
}

// ---------- GEMM 128x128: C[2048][N] = A[2048][K](bf16) * Bt[N][K](bf16)^T
// Counted-vmcnt pipeline (T4) + XOR-swizzled LDS (verified round 5).
// EPI 0: qkv-route; EPI 2: f32 = acc + res
template <int EPI>
__global__ __launch_bounds__(256) void kgemm(
    const u16* __restrict__ A, const u16* __restrict__ Bt, int N, int K,
    u16* o0, u16* __restrict__ o1, u16* __restrict__ o2,
    float* of, const float* res) {
  __shared__ u16 As[2][128 * 64];
  __shared__ u16 Bs[2][128 * 64];
  int bn = blockIdx.x * 128, bm = blockIdx.y * 128;
  int tid = threadIdx.x, lane = tid & 63, wv = tid >> 6;
  int wm = (wv >> 1) * 64, wn = (wv & 1) * 64;
  int r16 = lane & 15, grp = lane >> 4;
  int srow = lane >> 3;                    // 0..7: row within 8-row chunk
  int schunk = ((lane & 7) ^ srow) * 8;    // inverse-swizzled source k-offset
  f32x4 acc[4][4] = {};
  const u16* Abase = A + (size_t)(bm + wv * 32) * K + schunk;
  const u16* Bbase = Bt + (size_t)(bn + wv * 32) * K + schunk;
  int woff = wv * 32 * 64;

  auto STAGE = [&](int buf, int k0) {
#pragma unroll
    for (int j = 0; j < 4; ++j) {
      gld16(Abase + (size_t)(j * 8 + srow) * K + k0, &As[buf][woff + j * 512]);
      gld16(Bbase + (size_t)(j * 8 + srow) * K + k0, &Bs[buf][woff + j * 512]);
    }
  };
  auto COMPUTE = [&](int buf) {
#pragma unroll
    for (int kk = 0; kk < 2; ++kk) {
      int swz = (((kk << 2) | grp) ^ (r16 & 7)) * 8;
      bf16x8 af[4], bfr[4];
#pragma unroll
      for (int m = 0; m < 4; ++m)
        af[m] = *(const bf16x8*)&As[buf][(wm + m * 16 + r16) * 64 + swz];
#pragma unroll
      for (int n = 0; n < 4; ++n)
        bfr[n] = *(const bf16x8*)&Bs[buf][(wn + n * 16 + r16) * 64 + swz];
#pragma unroll
      for (int m = 0; m < 4; ++m)
#pragma unroll
        for (int n = 0; n < 4; ++n)
          acc[m][n] = __builtin_amdgcn_mfma_f32_16x16x32_bf16(af[m], bfr[n], acc[m][n], 0, 0, 0);
    }
  };

  STAGE(0, 0);
  int nt = K >> 6;
  for (int t = 0; t < nt; ++t) {
    int cur = t & 1;
    if (t + 1 < nt) {
      STAGE(cur ^ 1, (t + 1) << 6);
      asm volatile("s_waitcnt vmcnt(8)" ::: "memory");
    } else {
      asm volatile("s_waitcnt vmcnt(0)" ::: "memory");
    }
    __builtin_amdgcn_sched_barrier(0);
    __builtin_amdgcn_s_barrier();   // tile t visible to all waves
    __builtin_amdgcn_sched_barrier(0);
    COMPUTE(cur);
    __builtin_amdgcn_s_barrier();   // all waves done reading buf[cur]
  }

#pragma unroll
  for (int mi = 0; mi < 4; ++mi) {
#pragma unroll
    for (int ni = 0; ni < 4; ++ni) {
#pragma unroll
      for (int r = 0; r < 4; ++r) {
        int gr = bm + wm + mi * 16 + grp * 4 + r;
        int gc = bn + wn + ni * 16 + r16;
        float v = acc[mi][ni][r];
        if constexpr (EPI == 0) {
          if (gc < DIM) {
            o0[(size_t)gr * DIM + gc] = f2bf(v);
          } else if (gc < DIM + 512) {
            o1[(size_t)gr * 512 + (gc - DIM)] = f2bf(v);
          } else {
            int c2 = gc - (DIM + 512);
            of[(size_t)gr * 512 + c2] = v;
            o2[(size_t)gr * 512 + c2] = f2bf(v);
          }
        } else {
          of[(size_t)gr * N + gc] = v + res[(size_t)gr * N + gc];
        }
      }
    }
  }
}

// ---------- wide interleaved gate/up GEMM, 256x256 tile, 8 waves (2Mx4N).
// Bt rows: 2j = wg^T[:,j], 2j+1 = wu^T[:,j]  (N_wide = 11264).
// Same verified sync skeleton as kgemm. Epilogue: lane pairs (even=gate,
// odd=up) exchanged via shfl_xor(1); even lanes store silu(g)*u.
__global__ __launch_bounds__(512) void kgemm_gu256(
    const u16* __restrict__ A, const u16* __restrict__ Bt,
    u16* __restrict__ out) {
  const int K = DIM;
  __shared__ u16 As[2][256 * 64];
  __shared__ u16 Bs[2][256 * 64];
  int bn = blockIdx.x * 256, bm = blockIdx.y * 256;
  int tid = threadIdx.x, lane = tid & 63, wv = tid >> 6;  // 8 waves
  int wr = (wv >> 2) * 128;   // 0 / 128
  int wc = (wv & 3) * 64;     // 0..192
  int r16 = lane & 15, grp = lane >> 4;
  int srow = lane >> 3;
  int schunk = ((lane & 7) ^ srow) * 8;
  f32x4 acc[8][4] = {};
  const u16* Abase = A + (size_t)(bm + wv * 32) * K + schunk;
  const u16* Bbase = Bt + (size_t)(bn + wv * 32) * K + schunk;
  int woff = wv * 32 * 64;

  auto STAGE = [&](int buf, int k0) {
#pragma unroll
    for (int j = 0; j < 4; ++j) {
      gld16(Abase + (size_t)(j * 8 + srow) * K + k0, &As[buf][woff + j * 512]);
      gld16(Bbase + (size_t)(j * 8 + srow) * K + k0, &Bs[buf][woff + j * 512]);
    }
  };
  auto COMPUTE = [&](int buf) {
#pragma unroll
    for (int kk = 0; kk < 2; ++kk) {
      int swz = (((kk << 2) | grp) ^ (r16 & 7)) * 8;
      bf16x8 af[8], bfr[4];
#pragma unroll
      for (int m = 0; m < 8; ++m)
        af[m] = *(const bf16x8*)&As[buf][(wr + m * 16 + r16) * 64 + swz];
#pragma unroll
      for (int n = 0; n < 4; ++n)
        bfr[n] = *(const bf16x8*)&Bs[buf][(wc + n * 16 + r16) * 64 + swz];
#pragma unroll
      for (int m = 0; m < 8; ++m)
#pragma unroll
        for (int n = 0; n < 4; ++n)
          acc[m][n] = __builtin_amdgcn_mfma_f32_16x16x32_bf16(af[m], bfr[n], acc[m][n], 0, 0, 0);
    }
  };

  STAGE(0, 0);
  int nt = K >> 6;
  for (int t = 0; t < nt; ++t) {
    int cur = t & 1;
    if (t + 1 < nt) {
      STAGE(cur ^ 1, (t + 1) << 6);
      asm volatile("s_waitcnt vmcnt(8)" ::: "memory");
    } else {
      asm volatile("s_waitcnt vmcnt(0)" ::: "memory");
    }
    __builtin_amdgcn_sched_barrier(0);
    __builtin_amdgcn_s_barrier();
    __builtin_amdgcn_sched_barrier(0);
    COMPUTE(cur);
    __builtin_amdgcn_s_barrier();
  }

  bool evenlane = (r16 & 1) == 0;
#pragma unroll
  for (int mi = 0; mi < 8; ++mi) {
#pragma unroll
    for (int ni = 0; ni < 4; ++ni) {
#pragma unroll
      for (int r = 0; r < 4; ++r) {
        float v = acc[mi][ni][r];
        float pv = __shfl_xor(v, 1, 64);  // partner column (gate<->up)
        if (evenlane) {
          int gr = bm + wr + mi * 16 + grp * 4 + r;
          int gc = bn + wc + ni * 16 + r16;
          float sg = v / (1.0f + __expf(-v));
          out[(size_t)gr * FFNDIM + (gc >> 1)] = f2bf(sg * pv);
        }
      }
    }
  }
}

// ---------- causal GQA flash attention. 1 wave per (b, h, 16 q rows). KV tiles of 32.
// V consumed from pre-transposed Vt[b][g][d][s]: PV B-fragment = one bf16x8 load.
__global__ __launch_bounds__(64) void kattn(const u16* __restrict__ qb,
                                            const u16* __restrict__ kb,
                                            const u16* __restrict__ vtb,
                                            u16* __restrict__ ctxb) {
  __shared__ u16 Plds[16][40];
  int l = threadIdx.x;
  int qt = blockIdx.x, h = blockIdx.y, b = blockIdx.z;
  int g = h >> 2;  // J = NH/NKV = 4
  int q0 = qt * 16;
  int r16 = l & 15, grp = l >> 4;
  const float scale = 0.08838834764831845f;  // 1/sqrt(128)
  bf16x8 qf[4];
  {
    const u16* qrow = qb + (size_t)(b * SEQ + q0 + r16) * DIM + h * HD + grp * 8;
#pragma unroll
    for (int c = 0; c < 4; ++c) qf[c] = *(const bf16x8*)(qrow + c * 32);
  }
  const u16* vt = vtb + (size_t)(b * NKV + g) * HD * SEQ;
  f32x4 ctx[8] = {};
  float m = -1e30f, lsum = 0.0f;
  int q_idx = q0 + r16;
  int ttmax = (q0 + 15) >> 5;
  for (int tt = 0; tt <= ttmax; ++tt) {
    int t0 = tt * 32;
    f32x4 d0 = {0.f, 0.f, 0.f, 0.f}, d1 = {0.f, 0.f, 0.f, 0.f};
    const u16* krow0 = kb + (size_t)(b * SEQ + t0 + r16) * (NKV * HD) + g * HD + grp * 8;
    const u16* krow1 = krow0 + 16 * (NKV * HD);
#pragma unroll
    for (int c = 0; c < 4; ++c) {
      bf16x8 kf0 = *(const bf16x8*)(krow0 + c * 32);
      d0 = __builtin_amdgcn_mfma_f32_16x16x32_bf16(kf0, qf[c], d0, 0, 0, 0);
      bf16x8 kf1 = *(const bf16x8*)(krow1 + c * 32);
      d1 = __builtin_amdgcn_mfma_f32_16x16x32_bf16(kf1, qf[c], d1, 0, 0, 0);
    }
    // lane holds S[q = q0+r16][t = t0 + grp*4 + r (+16)]
    float p[8];
    float mx = -1e30f;
#pragma unroll
    for (int r = 0; r < 4; ++r) {
      int tA = t0 + grp * 4 + r;
      float sA = d0[r] * scale;
      if (tA > q_idx) sA = -1e30f;
      float sB = d1[r] * scale;
      if (tA + 16 > q_idx) sB = -1e30f;
      p[r] = sA; p[r + 4] = sB;
      mx = fmaxf(mx, fmaxf(sA, sB));
    }
    mx = fmaxf(mx, __shfl_xor(mx, 16, 64));
    mx = fmaxf(mx, __shfl_xor(mx, 32, 64));
    float mnew = fmaxf(m, mx);
    float psum = 0.f;
#pragma unroll
    for (int i = 0; i < 8; ++i) { p[i] = __expf(p[i] - mnew); psum += p[i]; }
    psum += __shfl_xor(psum, 16, 64);
    psum += __shfl_xor(psum, 32, 64);
    float corr = __expf(m - mnew);
    lsum = lsum * corr + psum;
    m = mnew;
    // P -> LDS in A-frag-friendly [q][t_rel] layout
    *(unsigned*)&Plds[r16][grp * 4] = (unsigned)f2bf(p[0]) | ((unsigned)f2bf(p[1]) << 16);
    *(unsigned*)&Plds[r16][grp * 4 + 2] = (unsigned)f2bf(p[2]) | ((unsigned)f2bf(p[3]) << 16);
    *(unsigned*)&Plds[r16][16 + grp * 4] = (unsigned)f2bf(p[4]) | ((unsigned)f2bf(p[5]) << 16);
    *(unsigned*)&Plds[r16][16 + grp * 4 + 2] = (unsigned)f2bf(p[6]) | ((unsigned)f2bf(p[7]) << 16);
    // rescale ctx (ctx reg r belongs to q_rel = grp*4+r; corr lives at lane q_rel)
    float cf[4];
#pragma unroll
    for (int r = 0; r < 4; ++r) cf[r] = __shfl(corr, grp * 4 + r, 64);
#pragma unroll
    for (int dc = 0; dc < 8; ++dc)
#pragma unroll
      for (int r = 0; r < 4; ++r) ctx[dc][r] *= cf[r];
    bf16x8 pa;
    {
      union { bf16x8 v; int4 q; } u;
      u.q = *(const int4*)&Plds[r16][grp * 8];
      pa = u.v;
    }
#pragma unroll
    for (int dc = 0; dc < 8; ++dc) {
      bf16x8 vf = *(const bf16x8*)(vt + (size_t)(dc * 16 + r16) * SEQ + t0 + grp * 8);
      ctx[dc] = __builtin_amdgcn_mfma_f32_16x16x32_bf16(pa, vf, ctx[dc], 0, 0, 0);
    }
  }
  float linv = 1.0f / lsum;
  float lf[4];
#pragma unroll
  for (int r = 0; r < 4; ++r) lf[r] = __shfl(linv, grp * 4 + r, 64);
  u16* crow = ctxb + (size_t)(b * SEQ + q0) * DIM + h * HD;
#pragma unroll
  for (int dc = 0; dc < 8; ++dc)
#pragma unroll
    for (int r = 0; r < 4; ++r)
      crow[(size_t)(grp * 4 + r) * DIM + dc * 16 + r16] = f2bf(ctx[dc][r] * lf[r]);
}

extern "C" void kernel_launch(void* const* d_in, const int* in_sizes, int n_in,
                              void* d_out, int out_size, void* d_ws, size_t ws_size,
                              hipStream_t stream) {
  const float* x = (const float*)d_in[0];
  const float* fc = (const float*)d_in[1];
  const float* wq = (const float*)d_in[5];
  const float* wk = (const float*)d_in[6];
  const float* wv = (const float*)d_in[7];
  const float* wo = (const float*)d_in[8];
  const float* wg = (const float*)d_in[9];
  const float* wu = (const float*)d_in[10];
  const float* wd = (const float*)d_in[11];
  const float* anw = (const float*)d_in[12];
  const float* fnw = (const float*)d_in[13];

  float* out_x = (float*)d_out;                       // [2048][2048] f32
  float* out_ck = out_x + (size_t)MROWS * DIM;        // [2048][512] f32
  float* out_cv = out_ck + (size_t)MROWS * NKV * HD;  // [2048][512] f32

  char* ws = (char*)d_ws;
  u16* h_b    = (u16*)(ws);                      // 8 MB   [2048][2048] bf16
  u16* q_b    = (u16*)(ws + (8u << 20));         // 8 MB   [2048][2048]
  u16* k_b    = (u16*)(ws + (16u << 20));        // 2 MB   [2048][512]
  u16* v_b    = (u16*)(ws + (18u << 20));        // 2 MB   [2048][512]
  u16* ctx_b  = (u16*)(ws + (20u << 20));        // 8 MB   [2048][2048]
  u16* hf_b   = (u16*)(ws + (28u << 20));        // 8 MB   [2048][2048]
  u16* Wt     = (u16*)(ws + (60u << 20));        // 12 MB  qkv^T, later wo^T
  u16* vt_b   = h_b;                             // reuse (attn phase)
  u16* Wt_gu  = (u16*)(ws + (36u << 20));        // 44 MB  [11264][2048] interleaved
  u16* g_b    = (u16*)(ws);                      // 22 MB  [2048][5632] silu*up (post-attn)
  u16* Wt_dn  = (u16*)(ws + (36u << 20));        // 22 MB  wd^T (post-gu)

  // QKV weights -> Wt rows [0,2048)=wq^T, [2048,2560)=wk^T, [2560,3072)=wv^T
  kxpose<<<dim3(2048 / 64, 2048 / 64), 256, 0, stream>>>(wq, Wt, 2048, 2048, 1, 0);
  kxpose<<<dim3(512 / 64, 2048 / 64), 256, 0, stream>>>(wk, Wt + (size_t)2048 * 2048, 2048, 512, 1, 0);
  kxpose<<<dim3(512 / 64, 2048 / 64), 256, 0, stream>>>(wv, Wt + (size_t)2560 * 2048, 2048, 512, 1, 0);

  krmsnorm<<<MROWS, 256, 0, stream>>>(x, anw, h_b);
  kgemm<0><<<dim3(3072 / 128, 16), 256, 0, stream>>>(h_b, Wt, 3072, 2048,
                                                     q_b, k_b, v_b, out_cv, nullptr);
  krope_q<<<8192, 256, 0, stream>>>(q_b, fc);
  krope_k<<<2048, 256, 0, stream>>>(k_b, fc, out_ck);
  kvxpose<<<dim3(SEQ / 64, HD / 64, BSZ * NKV), 256, 0, stream>>>(v_b, vt_b);
  kattn<<<dim3(SEQ / 16, NH, BSZ), 64, 0, stream>>>(q_b, k_b, vt_b, ctx_b);

  kxpose<<<dim3(32, 32), 256, 0, stream>>>(wo, Wt, 2048, 2048, 1, 0);
  kgemm<2><<<dim3(16, 16), 256, 0, stream>>>(ctx_b, Wt, 2048, 2048,
                                             nullptr, nullptr, nullptr, out_x, x);
  krmsnorm<<<MROWS, 256, 0, stream>>>(out_x, fnw, hf_b);

  // FFN: interleaved wide gate/up -> fused swiglu epilogue -> down
  kxpose<<<dim3(5632 / 64, 2048 / 64), 256, 0, stream>>>(wg, Wt_gu, 2048, 5632, 2, 0);
  kxpose<<<dim3(5632 / 64, 2048 / 64), 256, 0, stream>>>(wu, Wt_gu, 2048, 5632, 2, 1);
  kgemm_gu256<<<dim3(11264 / 256, 2048 / 256), 512, 0, stream>>>(hf_b, Wt_gu, g_b);
  kxpose<<<dim3(2048 / 64, 5632 / 64), 256, 0, stream>>>(wd, Wt_dn, 5632, 2048, 1, 0);
  kgemm<2><<<dim3(16, 16), 256, 0, stream>>>(g_b, Wt_dn, 2048, 5632,
                                             nullptr, nullptr, nullptr, out_x, out_x);
}

// Round 7
// 457.810 us; speedup vs baseline: 1.2765x; 1.1441x over previous
//
#include <hip/hip_runtime.h>

typedef float f32x4 __attribute__((ext_vector_type(4)));
typedef __bf16 bf16x8 __attribute__((ext_vector_type(8)));
typedef unsigned short u16;

#define DIM 2048
#define SEQ 1024
#define BSZ 2
#define NH 16
#define NKV 4
#define HD 128
#define FFNDIM 5632
#define MROWS (BSZ * SEQ)  // 2048

__device__ __forceinline__ u16 f2bf(float f) {
  union { float f; unsigned u; } v; v.f = f;
  unsigned u = v.u;
  unsigned r = (u + 0x7fffu + ((u >> 16) & 1u)) >> 16;  // RNE
  return (u16)r;
}
__device__ __forceinline__ float bf2f(u16 h) {
  union { unsigned u; float f; } v; v.u = ((unsigned)h) << 16; return v.f;
}

__device__ __forceinline__ void gld16(const void* g, void* l) {
  __builtin_amdgcn_global_load_lds(
      (const __attribute__((address_space(1))) unsigned int*)g,
      (__attribute__((address_space(3))) unsigned int*)l, 16, 0, 0);
}

// ---------- transpose + fp32->bf16 convert: W [K][N] f32 -> Wt[(n*rs+ro)][K] bf16
__global__ __launch_bounds__(256) void kxpose(const float* __restrict__ W,
                                              u16* __restrict__ Wt,
                                              int K, int N, int rs, int ro) {
  __shared__ float t[64][65];
  int kb = blockIdx.y * 64, nb = blockIdx.x * 64;
  int tid = threadIdx.x;
#pragma unroll
  for (int it = 0; it < 16; ++it) {
    int idx = it * 256 + tid;
    int r = idx >> 6, c = idx & 63;
    t[r][c] = W[(size_t)(kb + r) * N + nb + c];
  }
  __syncthreads();
#pragma unroll
  for (int it = 0; it < 16; ++it) {
    int idx = it * 256 + tid;
    int rn = idx >> 6, ck = idx & 63;
    Wt[((size_t)(nb + rn) * rs + ro) * K + kb + ck] = f2bf(t[ck][rn]);
  }
}

// ---------- V transpose: v [b*S+s][g*128+d] bf16 -> Vt [((b*4+g)*128+d)*S + s]
__global__ __launch_bounds__(256) void kvxpose(const u16* __restrict__ v,
                                               u16* __restrict__ vt) {
  __shared__ u16 t[64][66];
  int bg = blockIdx.z;
  int b = bg >> 2, g = bg & 3;
  int s0 = blockIdx.x * 64, d0 = blockIdx.y * 64;
  int tid = threadIdx.x;
  int rr = tid >> 4, cc = (tid & 15) * 4;
#pragma unroll
  for (int it = 0; it < 4; ++it) {
    int r = it * 16 + rr;
    *(uint2*)&t[r][cc] =
        *(const uint2*)(v + (size_t)(b * SEQ + s0 + r) * (NKV * HD) + g * HD + d0 + cc);
  }
  __syncthreads();
#pragma unroll
  for (int it = 0; it < 4; ++it) {
    int r = it * 16 + rr;  // d index within tile
    u16 o[4] = {t[cc][r], t[cc + 1][r], t[cc + 2][r], t[cc + 3][r]};
    *(uint2*)(vt + (size_t)((b * NKV + g) * HD + d0 + r) * SEQ + s0 + cc) = *(const uint2*)o;
  }
}

// ---------- RMSNorm: x [rows][2048] f32 -> out bf16
__global__ __launch_bounds__(256) void krmsnorm(const float* __restrict__ x,
                                                const float* __restrict__ w,
                                                u16* __restrict__ out) {
  int row = blockIdx.x, tid = threadIdx.x;
  const float* xr = x + (size_t)row * DIM;
  float4 a = *(const float4*)(xr + tid * 8);
  float4 b = *(const float4*)(xr + tid * 8 + 4);
  float ss = a.x * a.x + a.y * a.y + a.z * a.z + a.w * a.w +
             b.x * b.x + b.y * b.y + b.z * b.z + b.w * b.w;
#pragma unroll
  for (int off = 1; off < 64; off <<= 1) ss += __shfl_xor(ss, off, 64);
  __shared__ float red[4];
  if ((tid & 63) == 0) red[tid >> 6] = ss;
  __syncthreads();
  float tot = red[0] + red[1] + red[2] + red[3];
  float sc = rsqrtf(tot * (1.0f / DIM) + 1e-5f);
  float xs[8] = {a.x, a.y, a.z, a.w, b.x, b.y, b.z, b.w};
  const float* wr = w + tid * 8;
  u16 o[8];
#pragma unroll
  for (int j = 0; j < 8; ++j) o[j] = f2bf(xs[j] * sc * wr[j]);
  *(int4*)(out + (size_t)row * DIM + tid * 8) = *(const int4*)o;
}

// ---------- RoPE on q (in-place, bf16). one thread per (row, head, pair)
__global__ __launch_bounds__(256) void krope_q(u16* __restrict__ q,
                                               const float* __restrict__ fc) {
  int t = blockIdx.x * 256 + threadIdx.x;           // 2048*16*64 = 2^21
  int j = t & 63;
  int h = (t >> 6) & (NH - 1);
  int row = t >> 10;
  int s = row & (SEQ - 1);
  size_t off = (size_t)row * DIM + h * HD + 2 * j;
  unsigned pk = *(unsigned*)(q + off);
  float x0 = bf2f((u16)pk), x1 = bf2f((u16)(pk >> 16));
  float cs = fc[s * HD + 2 * j], sn = fc[s * HD + 2 * j + 1];
  float y0 = x0 * cs - x1 * sn;
  float y1 = x0 * sn + x1 * cs;
  *(unsigned*)(q + off) = (unsigned)f2bf(y0) | ((unsigned)f2bf(y1) << 16);
}

// ---------- RoPE on k (in-place bf16) + write fp32 cache_k
__global__ __launch_bounds__(256) void krope_k(u16* __restrict__ k,
                                               const float* __restrict__ fc,
                                               float* __restrict__ ck) {
  int t = blockIdx.x * 256 + threadIdx.x;           // 2048*4*64 = 2^19
  int j = t & 63;
  int g = (t >> 6) & (NKV - 1);
  int row = t >> 8;
  int s = row & (SEQ - 1);
  size_t off = (size_t)row * (NKV * HD) + g * HD + 2 * j;
  unsigned pk = *(unsigned*)(k + off);
  float x0 = bf2f((u16)pk), x1 = bf2f((u16)(pk >> 16));
  float cs = fc[s * HD + 2 * j], sn = fc[s * HD + 2 * j + 1];
  float y0 = x0 * cs - x1 * sn;
  float y1 = x0 * sn + x1 * cs;
  *(unsigned*)(k + off) = (unsigned)f2bf(y0) | ((unsigned)f2bf(y1) << 16);
  ck[off] = y0;
  ck[off + 1] = y1;
}

// ---------- GEMM 128x128, 8 waves (2Mx4N, wave tile 64x32):
// C[2048][N] = A[2048][K](bf16) * Bt[N][K](bf16)^T
// Counted-vmcnt pipeline (validated r5/r6) + XOR-swizzled LDS.
// 64KB LDS + ~112 unified regs -> 2 blocks/CU (4 waves/SIMD).
// EPI 0: qkv-route; EPI 2: f32 = acc + res
template <int EPI>
__global__ __launch_bounds__(512, 4) void kgemm(
    const u16* __restrict__ A, const u16* __restrict__ Bt, int N, int K,
    u16* o0, u16* __restrict__ o1, u16* __restrict__ o2,
    float* of, const float* res) {
  __shared__ u16 As[2][128 * 64];
  __shared__ u16 Bs[2][128 * 64];
  int bn = blockIdx.x * 128, bm = blockIdx.y * 128;
  int tid = threadIdx.x, lane = tid & 63, wv = tid >> 6;  // 8 waves
  int wm = (wv >> 2) * 64;   // 0 / 64
  int wn = (wv & 3) * 32;    // 0..96
  int r16 = lane & 15, grp = lane >> 4;
  int srow = lane >> 3;                    // 0..7: row within 8-row chunk
  int schunk = ((lane & 7) ^ srow) * 8;    // inverse-swizzled source k-offset
  f32x4 acc[4][2] = {};
  // wave wv stages rows [wv*16, wv*16+16) of both tiles
  const u16* Abase = A + (size_t)(bm + wv * 16) * K + schunk;
  const u16* Bbase = Bt + (size_t)(bn + wv * 16) * K + schunk;
  int woff = wv * 16 * 64;

  auto STAGE = [&](int buf, int k0) {
#pragma unroll
    for (int j = 0; j < 2; ++j) {
      gld16(Abase + (size_t)(j * 8 + srow) * K + k0, &As[buf][woff + j * 512]);
      gld16(Bbase + (size_t)(j * 8 + srow) * K + k0, &Bs[buf][woff + j * 512]);
    }
  };
  auto COMPUTE = [&](int buf) {
#pragma unroll
    for (int kk = 0; kk < 2; ++kk) {
      int swz = (((kk << 2) | grp) ^ (r16 & 7)) * 8;
      bf16x8 af[4], bfr[2];
#pragma unroll
      for (int m = 0; m < 4; ++m)
        af[m] = *(const bf16x8*)&As[buf][(wm + m * 16 + r16) * 64 + swz];
#pragma unroll
      for (int n = 0; n < 2; ++n)
        bfr[n] = *(const bf16x8*)&Bs[buf][(wn + n * 16 + r16) * 64 + swz];
#pragma unroll
      for (int m = 0; m < 4; ++m)
#pragma unroll
        for (int n = 0; n < 2; ++n)
          acc[m][n] = __builtin_amdgcn_mfma_f32_16x16x32_bf16(af[m], bfr[n], acc[m][n], 0, 0, 0);
    }
  };

  STAGE(0, 0);
  int nt = K >> 6;
  for (int t = 0; t < nt; ++t) {
    int cur = t & 1;
    if (t + 1 < nt) {
      STAGE(cur ^ 1, (t + 1) << 6);
      asm volatile("s_waitcnt vmcnt(4)" ::: "memory");
    } else {
      asm volatile("s_waitcnt vmcnt(0)" ::: "memory");
    }
    __builtin_amdgcn_sched_barrier(0);
    __builtin_amdgcn_s_barrier();   // tile t visible to all waves
    __builtin_amdgcn_sched_barrier(0);
    COMPUTE(cur);
    __builtin_amdgcn_s_barrier();   // all waves done reading buf[cur]
  }

#pragma unroll
  for (int mi = 0; mi < 4; ++mi) {
#pragma unroll
    for (int ni = 0; ni < 2; ++ni) {
#pragma unroll
      for (int r = 0; r < 4; ++r) {
        int gr = bm + wm + mi * 16 + grp * 4 + r;
        int gc = bn + wn + ni * 16 + r16;
        float v = acc[mi][ni][r];
        if constexpr (EPI == 0) {
          if (gc < DIM) {
            o0[(size_t)gr * DIM + gc] = f2bf(v);
          } else if (gc < DIM + 512) {
            o1[(size_t)gr * 512 + (gc - DIM)] = f2bf(v);
          } else {
            int c2 = gc - (DIM + 512);
            of[(size_t)gr * 512 + c2] = v;
            o2[(size_t)gr * 512 + c2] = f2bf(v);
          }
        } else {
          of[(size_t)gr * N + gc] = v + res[(size_t)gr * N + gc];
        }
      }
    }
  }
}

// ---------- interleaved gate/up GEMM, 128x128 tile, 8 waves.
// Bt rows: 2j = wg^T[:,j], 2j+1 = wu^T[:,j]  (N_wide = 11264).
// Epilogue: lane pairs (even=gate, odd=up) exchanged via shfl_xor(1);
// even lanes store silu(g)*u.
__global__ __launch_bounds__(512, 4) void kgemm_gu(
    const u16* __restrict__ A, const u16* __restrict__ Bt,
    u16* __restrict__ out) {
  const int K = DIM;
  __shared__ u16 As[2][128 * 64];
  __shared__ u16 Bs[2][128 * 64];
  int bn = blockIdx.x * 128, bm = blockIdx.y * 128;
  int tid = threadIdx.x, lane = tid & 63, wv = tid >> 6;
  int wm = (wv >> 2) * 64;
  int wn = (wv & 3) * 32;
  int r16 = lane & 15, grp = lane >> 4;
  int srow = lane >> 3;
  int schunk = ((lane & 7) ^ srow) * 8;
  f32x4 acc[4][2] = {};
  const u16* Abase = A + (size_t)(bm + wv * 16) * K + schunk;
  const u16* Bbase = Bt + (size_t)(bn + wv * 16) * K + schunk;
  int woff = wv * 16 * 64;

  auto STAGE = [&](int buf, int k0) {
#pragma unroll
    for (int j = 0; j < 2; ++j) {
      gld16(Abase + (size_t)(j * 8 + srow) * K + k0, &As[buf][woff + j * 512]);
      gld16(Bbase + (size_t)(j * 8 + srow) * K + k0, &Bs[buf][woff + j * 512]);
    }
  };
  auto COMPUTE = [&](int buf) {
#pragma unroll
    for (int kk = 0; kk < 2; ++kk) {
      int swz = (((kk << 2) | grp) ^ (r16 & 7)) * 8;
      bf16x8 af[4], bfr[2];
#pragma unroll
      for (int m = 0; m < 4; ++m)
        af[m] = *(const bf16x8*)&As[buf][(wm + m * 16 + r16) * 64 + swz];
#pragma unroll
      for (int n = 0; n < 2; ++n)
        bfr[n] = *(const bf16x8*)&Bs[buf][(wn + n * 16 + r16) * 64 + swz];
#pragma unroll
      for (int m = 0; m < 4; ++m)
#pragma unroll
        for (int n = 0; n < 2; ++n)
          acc[m][n] = __builtin_amdgcn_mfma_f32_16x16x32_bf16(af[m], bfr[n], acc[m][n], 0, 0, 0);
    }
  };

  STAGE(0, 0);
  int nt = K >> 6;
  for (int t = 0; t < nt; ++t) {
    int cur = t & 1;
    if (t + 1 < nt) {
      STAGE(cur ^ 1, (t + 1) << 6);
      asm volatile("s_waitcnt vmcnt(4)" ::: "memory");
    } else {
      asm volatile("s_waitcnt vmcnt(0)" ::: "memory");
    }
    __builtin_amdgcn_sched_barrier(0);
    __builtin_amdgcn_s_barrier();
    __builtin_amdgcn_sched_barrier(0);
    COMPUTE(cur);
    __builtin_amdgcn_s_barrier();
  }

  bool evenlane = (r16 & 1) == 0;
#pragma unroll
  for (int mi = 0; mi < 4; ++mi) {
#pragma unroll
    for (int ni = 0; ni < 2; ++ni) {
#pragma unroll
      for (int r = 0; r < 4; ++r) {
        float v = acc[mi][ni][r];
        float pv = __shfl_xor(v, 1, 64);  // partner column (gate<->up)
        if (evenlane) {
          int gr = bm + wm + mi * 16 + grp * 4 + r;
          int gc = bn + wn + ni * 16 + r16;
          float sg = v / (1.0f + __expf(-v));
          out[(size_t)gr * FFNDIM + (gc >> 1)] = f2bf(sg * pv);
        }
      }
    }
  }
}

// ---------- causal GQA flash attention. 1 wave per (b, h, 16 q rows). KV tiles of 32.
// V consumed from pre-transposed Vt[b][g][d][s]: PV B-fragment = one bf16x8 load.
__global__ __launch_bounds__(64) void kattn(const u16* __restrict__ qb,
                                            const u16* __restrict__ kb,
                                            const u16* __restrict__ vtb,
                                            u16* __restrict__ ctxb) {
  __shared__ u16 Plds[16][40];
  int l = threadIdx.x;
  int qt = blockIdx.x, h = blockIdx.y, b = blockIdx.z;
  int g = h >> 2;  // J = NH/NKV = 4
  int q0 = qt * 16;
  int r16 = l & 15, grp = l >> 4;
  const float scale = 0.08838834764831845f;  // 1/sqrt(128)
  bf16x8 qf[4];
  {
    const u16* qrow = qb + (size_t)(b * SEQ + q0 + r16) * DIM + h * HD + grp * 8;
#pragma unroll
    for (int c = 0; c < 4; ++c) qf[c] = *(const bf16x8*)(qrow + c * 32);
  }
  const u16* vt = vtb + (size_t)(b * NKV + g) * HD * SEQ;
  f32x4 ctx[8] = {};
  float m = -1e30f, lsum = 0.0f;
  int q_idx = q0 + r16;
  int ttmax = (q0 + 15) >> 5;
  for (int tt = 0; tt <= ttmax; ++tt) {
    int t0 = tt * 32;
    f32x4 d0 = {0.f, 0.f, 0.f, 0.f}, d1 = {0.f, 0.f, 0.f, 0.f};
    const u16* krow0 = kb + (size_t)(b * SEQ + t0 + r16) * (NKV * HD) + g * HD + grp * 8;
    const u16* krow1 = krow0 + 16 * (NKV * HD);
#pragma unroll
    for (int c = 0; c < 4; ++c) {
      bf16x8 kf0 = *(const bf16x8*)(krow0 + c * 32);
      d0 = __builtin_amdgcn_mfma_f32_16x16x32_bf16(kf0, qf[c], d0, 0, 0, 0);
      bf16x8 kf1 = *(const bf16x8*)(krow1 + c * 32);
      d1 = __builtin_amdgcn_mfma_f32_16x16x32_bf16(kf1, qf[c], d1, 0, 0, 0);
    }
    // lane holds S[q = q0+r16][t = t0 + grp*4 + r (+16)]
    float p[8];
    float mx = -1e30f;
#pragma unroll
    for (int r = 0; r < 4; ++r) {
      int tA = t0 + grp * 4 + r;
      float sA = d0[r] * scale;
      if (tA > q_idx) sA = -1e30f;
      float sB = d1[r] * scale;
      if (tA + 16 > q_idx) sB = -1e30f;
      p[r] = sA; p[r + 4] = sB;
      mx = fmaxf(mx, fmaxf(sA, sB));
    }
    mx = fmaxf(mx, __shfl_xor(mx, 16, 64));
    mx = fmaxf(mx, __shfl_xor(mx, 32, 64));
    float mnew = fmaxf(m, mx);
    float psum = 0.f;
#pragma unroll
    for (int i = 0; i < 8; ++i) { p[i] = __expf(p[i] - mnew); psum += p[i]; }
    psum += __shfl_xor(psum, 16, 64);
    psum += __shfl_xor(psum, 32, 64);
    float corr = __expf(m - mnew);
    lsum = lsum * corr + psum;
    m = mnew;
    // P -> LDS in A-frag-friendly [q][t_rel] layout
    *(unsigned*)&Plds[r16][grp * 4] = (unsigned)f2bf(p[0]) | ((unsigned)f2bf(p[1]) << 16);
    *(unsigned*)&Plds[r16][grp * 4 + 2] = (unsigned)f2bf(p[2]) | ((unsigned)f2bf(p[3]) << 16);
    *(unsigned*)&Plds[r16][16 + grp * 4] = (unsigned)f2bf(p[4]) | ((unsigned)f2bf(p[5]) << 16);
    *(unsigned*)&Plds[r16][16 + grp * 4 + 2] = (unsigned)f2bf(p[6]) | ((unsigned)f2bf(p[7]) << 16);
    // rescale ctx (ctx reg r belongs to q_rel = grp*4+r; corr lives at lane q_rel)
    float cf[4];
#pragma unroll
    for (int r = 0; r < 4; ++r) cf[r] = __shfl(corr, grp * 4 + r, 64);
#pragma unroll
    for (int dc = 0; dc < 8; ++dc)
#pragma unroll
      for (int r = 0; r < 4; ++r) ctx[dc][r] *= cf[r];
    bf16x8 pa;
    {
      union { bf16x8 v; int4 q; } u;
      u.q = *(const int4*)&Plds[r16][grp * 8];
      pa = u.v;
    }
#pragma unroll
    for (int dc = 0; dc < 8; ++dc) {
      bf16x8 vf = *(const bf16x8*)(vt + (size_t)(dc * 16 + r16) * SEQ + t0 + grp * 8);
      ctx[dc] = __builtin_amdgcn_mfma_f32_16x16x32_bf16(pa, vf, ctx[dc], 0, 0, 0);
    }
  }
  float linv = 1.0f / lsum;
  float lf[4];
#pragma unroll
  for (int r = 0; r < 4; ++r) lf[r] = __shfl(linv, grp * 4 + r, 64);
  u16* crow = ctxb + (size_t)(b * SEQ + q0) * DIM + h * HD;
#pragma unroll
  for (int dc = 0; dc < 8; ++dc)
#pragma unroll
    for (int r = 0; r < 4; ++r)
      crow[(size_t)(grp * 4 + r) * DIM + dc * 16 + r16] = f2bf(ctx[dc][r] * lf[r]);
}

extern "C" void kernel_launch(void* const* d_in, const int* in_sizes, int n_in,
                              void* d_out, int out_size, void* d_ws, size_t ws_size,
                              hipStream_t stream) {
  const float* x = (const float*)d_in[0];
  const float* fc = (const float*)d_in[1];
  const float* wq = (const float*)d_in[5];
  const float* wk = (const float*)d_in[6];
  const float* wv = (const float*)d_in[7];
  const float* wo = (const float*)d_in[8];
  const float* wg = (const float*)d_in[9];
  const float* wu = (const float*)d_in[10];
  const float* wd = (const float*)d_in[11];
  const float* anw = (const float*)d_in[12];
  const float* fnw = (const float*)d_in[13];

  float* out_x = (float*)d_out;                       // [2048][2048] f32
  float* out_ck = out_x + (size_t)MROWS * DIM;        // [2048][512] f32
  float* out_cv = out_ck + (size_t)MROWS * NKV * HD;  // [2048][512] f32

  char* ws = (char*)d_ws;
  u16* h_b    = (u16*)(ws);                      // 8 MB   [2048][2048] bf16
  u16* q_b    = (u16*)(ws + (8u << 20));         // 8 MB   [2048][2048]
  u16* k_b    = (u16*)(ws + (16u << 20));        // 2 MB   [2048][512]
  u16* v_b    = (u16*)(ws + (18u << 20));        // 2 MB   [2048][512]
  u16* ctx_b  = (u16*)(ws + (20u << 20));        // 8 MB   [2048][2048]
  u16* hf_b   = (u16*)(ws + (28u << 20));        // 8 MB   [2048][2048]
  u16* Wt     = (u16*)(ws + (60u << 20));        // 12 MB  qkv^T, later wo^T
  u16* vt_b   = h_b;                             // reuse (attn phase)
  u16* Wt_gu  = (u16*)(ws + (36u << 20));        // 44 MB  [11264][2048] interleaved
  u16* g_b    = (u16*)(ws);                      // 22 MB  [2048][5632] silu*up (post-attn)
  u16* Wt_dn  = (u16*)(ws + (36u << 20));        // 22 MB  wd^T (post-gu)

  // QKV weights -> Wt rows [0,2048)=wq^T, [2048,2560)=wk^T, [2560,3072)=wv^T
  kxpose<<<dim3(2048 / 64, 2048 / 64), 256, 0, stream>>>(wq, Wt, 2048, 2048, 1, 0);
  kxpose<<<dim3(512 / 64, 2048 / 64), 256, 0, stream>>>(wk, Wt + (size_t)2048 * 2048, 2048, 512, 1, 0);
  kxpose<<<dim3(512 / 64, 2048 / 64), 256, 0, stream>>>(wv, Wt + (size_t)2560 * 2048, 2048, 512, 1, 0);

  krmsnorm<<<MROWS, 256, 0, stream>>>(x, anw, h_b);
  kgemm<0><<<dim3(3072 / 128, 16), 512, 0, stream>>>(h_b, Wt, 3072, 2048,
                                                     q_b, k_b, v_b, out_cv, nullptr);
  krope_q<<<8192, 256, 0, stream>>>(q_b, fc);
  krope_k<<<2048, 256, 0, stream>>>(k_b, fc, out_ck);
  kvxpose<<<dim3(SEQ / 64, HD / 64, BSZ * NKV), 256, 0, stream>>>(v_b, vt_b);
  kattn<<<dim3(SEQ / 16, NH, BSZ), 64, 0, stream>>>(q_b, k_b, vt_b, ctx_b);

  kxpose<<<dim3(32, 32), 256, 0, stream>>>(wo, Wt, 2048, 2048, 1, 0);
  kgemm<2><<<dim3(16, 16), 512, 0, stream>>>(ctx_b, Wt, 2048, 2048,
                                             nullptr, nullptr, nullptr, out_x, x);
  krmsnorm<<<MROWS, 256, 0, stream>>>(out_x, fnw, hf_b);

  // FFN: interleaved gate/up -> fused swiglu epilogue -> down
  kxpose<<<dim3(5632 / 64, 2048 / 64), 256, 0, stream>>>(wg, Wt_gu, 2048, 5632, 2, 0);
  kxpose<<<dim3(5632 / 64, 2048 / 64), 256, 0, stream>>>(wu, Wt_gu, 2048, 5632, 2, 1);
  kgemm_gu<<<dim3(11264 / 128, 16), 512, 0, stream>>>(hf_b, Wt_gu, g_b);
  kxpose<<<dim3(2048 / 64, 5632 / 64), 256, 0, stream>>>(wd, Wt_dn, 5632, 2048, 1, 0);
  kgemm<2><<<dim3(16, 16), 512, 0, stream>>>(g_b, Wt_dn, 2048, 5632,
                                             nullptr, nullptr, nullptr, out_x, out_x);
}